// Round 1
// baseline (211.969 us; speedup 1.0000x reference)
//
#include <hip/hip_runtime.h>
#include <math.h>

// Problem constants (fixed by setup_inputs)
constexpr int N = 8192;   // rows
constexpr int D = 512;    // feature dim
constexpr int C = 64;     // classes
constexpr int LIST_CAP = 2048;  // per-class row-list cap (actual counts ~128±12)
constexpr double TOTAL_PAIRS = 33550336.0;  // N*(N-1)/2

// ws layout (float elements):
//   [0, 32768)        S[c][d]   per-class column sums
//   [32768, 32832)    Q[c]      per-class sum of sq
//   [32832, 32896)    n[c]      per-class counts (as unsigned)
//   [32896]           cross_sum (atomic fp32 accumulator)
//   [32900, 41092)    lbl[N]    (int)
//   [41092, 49284)    sq[N]
// total: 49284 floats = ~197 KB

// ---------------- kernel 1: per-row argmax + sum-of-squares ----------------
// one wave (64 lanes) per row; grid = N/4 blocks of 256
__global__ __launch_bounds__(256) void k_rows(const float* __restrict__ X,
                                              const float* __restrict__ L,
                                              int* __restrict__ lbl,
                                              float* __restrict__ sq,
                                              float* __restrict__ cross_sum) {
    if (blockIdx.x == 0 && threadIdx.x == 0) *cross_sum = 0.f;
    int wv = threadIdx.x >> 6, lane = threadIdx.x & 63;
    int row = blockIdx.x * 4 + wv;
    if (row >= N) return;

    // argmax over 64 label logits: lane l holds class l (first-max tie rule)
    float v = L[(size_t)row * C + lane];
    int idx = lane;
#pragma unroll
    for (int off = 1; off < 64; off <<= 1) {
        float ov = __shfl_xor(v, off);
        int oi = __shfl_xor(idx, off);
        if (ov > v || (ov == v && oi < idx)) { v = ov; idx = oi; }
    }

    // sum of squares: lane reads 8 contiguous floats (2x float4)
    const float4* Xr = (const float4*)(X + (size_t)row * D);
    float4 a = Xr[lane * 2], b = Xr[lane * 2 + 1];
    float s = a.x * a.x + a.y * a.y + a.z * a.z + a.w * a.w
            + b.x * b.x + b.y * b.y + b.z * b.z + b.w * b.w;
#pragma unroll
    for (int off = 1; off < 64; off <<= 1) s += __shfl_xor(s, off);

    if (lane == 0) { lbl[row] = idx; sq[row] = s; }
}

// -------- kernel 2: deterministic per-class sums (no global atomics) --------
// grid = C*4 blocks: block (c, colgroup g) sums columns [g*128, g*128+128)
// over rows of class c. block = 128 threads (one col each).
__global__ __launch_bounds__(128) void k_classsum(const float* __restrict__ X,
                                                  const int* __restrict__ lbl,
                                                  const float* __restrict__ sq,
                                                  float* __restrict__ S,
                                                  float* __restrict__ Q,
                                                  unsigned* __restrict__ ncls) {
    int c = blockIdx.x >> 2;
    int g = blockIdx.x & 3;
    __shared__ int list[LIST_CAP];
    __shared__ unsigned cnt;
    __shared__ float qred[128];
    if (threadIdx.x == 0) cnt = 0;
    __syncthreads();
    for (int r = threadIdx.x; r < N; r += 128) {
        if (lbl[r] == c) {
            unsigned p = atomicAdd(&cnt, 1u);
            if (p < LIST_CAP) list[p] = r;
        }
    }
    __syncthreads();
    int n = (int)min(cnt, (unsigned)LIST_CAP);
    int col = g * 128 + threadIdx.x;

    // 8-way unrolled indexed gather: 8 independent loads in flight
    float acc[8] = {0, 0, 0, 0, 0, 0, 0, 0};
    int k = 0;
    for (; k + 8 <= n; k += 8) {
#pragma unroll
        for (int u = 0; u < 8; u++)
            acc[u] += X[(size_t)list[k + u] * D + col];
    }
    for (; k < n; k++) acc[0] += X[(size_t)list[k] * D + col];
    float t = ((acc[0] + acc[1]) + (acc[2] + acc[3]))
            + ((acc[4] + acc[5]) + (acc[6] + acc[7]));
    S[(size_t)c * D + col] = t;

    if (g == 0) {  // colgroup 0 also writes Q_c and n_c
        float qs = 0.f;
        for (int k2 = threadIdx.x; k2 < n; k2 += 128) qs += sq[list[k2]];
        qred[threadIdx.x] = qs;
        __syncthreads();
        for (int s2 = 64; s2 > 0; s2 >>= 1) {
            if (threadIdx.x < s2) qred[threadIdx.x] += qred[threadIdx.x + s2];
            __syncthreads();
        }
        if (threadIdx.x == 0) { Q[c] = qred[0]; ncls[c] = (unsigned)n; }
    }
}

// ---------------- kernel 3: cross-class hinge term ----------------
// pairs (i: lbl==m2, j: lbl==m1), full bipartite (reference has no triu here).
// wave per i-row, streams all j-rows; 64-lane dot product.
__global__ __launch_bounds__(256) void k_cross(const float* __restrict__ X,
                                               const int* __restrict__ lbl,
                                               const float* __restrict__ sq,
                                               const unsigned* __restrict__ ncls,
                                               float* __restrict__ cross_sum) {
    // derive m1 (largest present class), m2 (second largest)
    int m1 = -1, m2 = -1;
    for (int c = C - 1; c >= 0; c--) {
        if (ncls[c] > 0) {
            if (m1 < 0) m1 = c;
            else { m2 = c; break; }
        }
    }
    if (m2 < 0) return;  // fewer than 2 classes -> diff term is 0

    __shared__ int A[LIST_CAP];  // rows with lbl==m2 (i side)
    __shared__ int B[LIST_CAP];  // rows with lbl==m1 (j side)
    __shared__ unsigned na_s, nb_s;
    if (threadIdx.x == 0) { na_s = 0; nb_s = 0; }
    __syncthreads();
    for (int r = threadIdx.x; r < N; r += 256) {
        int l = lbl[r];
        if (l == m2) { unsigned p = atomicAdd(&na_s, 1u); if (p < LIST_CAP) A[p] = r; }
        else if (l == m1) { unsigned p = atomicAdd(&nb_s, 1u); if (p < LIST_CAP) B[p] = r; }
    }
    __syncthreads();
    int na = (int)min(na_s, (unsigned)LIST_CAP);
    int nb = (int)min(nb_s, (unsigned)LIST_CAP);

    int wv = threadIdx.x >> 6, lane = threadIdx.x & 63;
    int gw = blockIdx.x * 4 + wv, nw = gridDim.x * 4;
    float hs = 0.f;
    for (int ai = gw; ai < na; ai += nw) {
        int i = A[ai];
        const float4* Xi = (const float4*)(X + (size_t)i * D);
        float4 ia = Xi[lane * 2], ib = Xi[lane * 2 + 1];
        float sqi = sq[i];
        for (int bi = 0; bi < nb; bi++) {
            int j = B[bi];
            const float4* Xj = (const float4*)(X + (size_t)j * D);
            float4 ja = Xj[lane * 2], jb = Xj[lane * 2 + 1];
            float d = ia.x * ja.x + ia.y * ja.y + ia.z * ja.z + ia.w * ja.w
                    + ib.x * jb.x + ib.y * jb.y + ib.z * jb.z + ib.w * jb.w;
#pragma unroll
            for (int off = 1; off < 64; off <<= 1) d += __shfl_xor(d, off);
            float d2 = fmaxf(sqi + sq[j] - 2.f * d, 0.f);
            float rt = sqrtf(d2);
            if (rt < 1.f) { float h = 1.f - rt; hs += h * h; }
        }
    }
    if (lane == 0 && hs != 0.f) atomicAdd(cross_sum, hs);
}

// ---------------- kernel 4: final combine (double precision) ----------------
__global__ __launch_bounds__(256) void k_final(const float* __restrict__ S,
                                               const float* __restrict__ Q,
                                               const unsigned* __restrict__ ncls,
                                               const float* __restrict__ cross_sum,
                                               float* __restrict__ out) {
    __shared__ double r2[256], r1[256], rc[256];
    double t2 = 0.0;
    for (int i = threadIdx.x; i < C * D; i += 256) {
        double s = S[i];
        t2 += s * s;
    }
    double t1 = 0.0, cnt = 0.0;
    if (threadIdx.x < C) {
        double nc = (double)ncls[threadIdx.x];
        t1 = nc * (double)Q[threadIdx.x];
        cnt = nc * (nc - 1.0) * 0.5;
    }
    r2[threadIdx.x] = t2;
    r1[threadIdx.x] = t1;
    rc[threadIdx.x] = cnt;
    __syncthreads();
    for (int s = 128; s > 0; s >>= 1) {
        if (threadIdx.x < s) {
            r2[threadIdx.x] += r2[threadIdx.x + s];
            r1[threadIdx.x] += r1[threadIdx.x + s];
            rc[threadIdx.x] += rc[threadIdx.x + s];
        }
        __syncthreads();
    }
    if (threadIdx.x == 0) {
        double same = (rc[0] > 0.0) ? (r1[0] - r2[0]) / rc[0] : 0.0;
        double diff = (double)cross_sum[0] / TOTAL_PAIRS;
        out[0] = (float)(same + diff);
    }
}

extern "C" void kernel_launch(void* const* d_in, const int* in_sizes, int n_in,
                              void* d_out, int out_size, void* d_ws, size_t ws_size,
                              hipStream_t stream) {
    const float* X = (const float*)d_in[0];   // outputs [N, D] fp32
    const float* L = (const float*)d_in[1];   // labels  [N, C] fp32
    float* ws = (float*)d_ws;

    float* S = ws;                           // 32768
    float* Q = ws + 32768;                   // 64
    unsigned* ncls = (unsigned*)(ws + 32832); // 64
    float* cross = ws + 32896;               // 1
    int* lbl = (int*)(ws + 32900);           // N
    float* sq = ws + 41092;                  // N
    float* out = (float*)d_out;

    hipLaunchKernelGGL(k_rows, dim3(N / 4), dim3(256), 0, stream, X, L, lbl, sq, cross);
    hipLaunchKernelGGL(k_classsum, dim3(C * 4), dim3(128), 0, stream, X, lbl, sq, S, Q, ncls);
    hipLaunchKernelGGL(k_cross, dim3(128), dim3(256), 0, stream, X, lbl, sq, ncls, cross);
    hipLaunchKernelGGL(k_final, dim3(1), dim3(256), 0, stream, S, Q, ncls, cross, out);
}

// Round 2
// 132.412 us; speedup vs baseline: 1.6008x; 1.6008x over previous
//
#include <hip/hip_runtime.h>
#include <math.h>

// Problem constants (fixed by setup_inputs)
constexpr int N = 8192;   // rows
constexpr int D = 512;    // feature dim
constexpr int C = 64;     // classes
constexpr int CAP_PC = 512;  // per-class list cap (counts ~128 +/- 11; 512 = 34 sigma)
constexpr double TOTAL_PAIRS = 33550336.0;  // N*(N-1)/2

// ws layout (32-bit elements):
//   [0, 32768)        S[c][d]       per-class column sums
//   [32768, 32832)    Q[c]          per-class sum of sq
//   [32832, 32896)    cnt[c]        per-class counts (u32, memset 0)
//   [32896]           cross_sum     (f32, memset 0)
//   [32900, 41092)    lbl[N]        (int)
//   [41092, 49284)    sq[N]
//   [49284, 82052)    cls_list[C][CAP_PC] (int)
// total ~328 KB

// ------- kernel 1: per-row argmax + sum-of-squares + class-list append -------
// one wave per row; grid = N/4 blocks of 256
__global__ __launch_bounds__(256) void k_rows(const float* __restrict__ X,
                                              const float* __restrict__ L,
                                              int* __restrict__ lbl,
                                              float* __restrict__ sq,
                                              unsigned* __restrict__ cnt,
                                              int* __restrict__ cls_list) {
    int wv = threadIdx.x >> 6, lane = threadIdx.x & 63;
    int row = blockIdx.x * 4 + wv;  // grid covers N exactly

    // argmax over 64 label logits: lane l holds class l (first-max tie rule)
    float v = L[(size_t)row * C + lane];
    int idx = lane;
#pragma unroll
    for (int off = 1; off < 64; off <<= 1) {
        float ov = __shfl_xor(v, off);
        int oi = __shfl_xor(idx, off);
        if (ov > v || (ov == v && oi < idx)) { v = ov; idx = oi; }
    }

    // sum of squares: lane reads 8 contiguous floats (2x float4)
    const float4* Xr = (const float4*)(X + (size_t)row * D);
    float4 a = Xr[lane * 2], b = Xr[lane * 2 + 1];
    float s = a.x * a.x + a.y * a.y + a.z * a.z + a.w * a.w
            + b.x * b.x + b.y * b.y + b.z * b.z + b.w * b.w;
#pragma unroll
    for (int off = 1; off < 64; off <<= 1) s += __shfl_xor(s, off);

    if (lane == 0) {
        lbl[row] = idx;
        sq[row] = s;
        unsigned p = atomicAdd(&cnt[idx], 1u);  // 64 counters, low contention
        if (p < CAP_PC) cls_list[idx * CAP_PC + p] = row;
    }
}

// -------- kernel 2: per-class column sums (list from global, no N-scan) --------
// grid = C*4 blocks: block (c, g) sums columns [g*128, g*128+128)
__global__ __launch_bounds__(128) void k_classsum(const float* __restrict__ X,
                                                  const int* __restrict__ cls_list,
                                                  const unsigned* __restrict__ cnt,
                                                  const float* __restrict__ sq,
                                                  float* __restrict__ S,
                                                  float* __restrict__ Q) {
    int c = blockIdx.x >> 2;
    int g = blockIdx.x & 3;
    int n = (int)min(cnt[c], (unsigned)CAP_PC);
    __shared__ int list[CAP_PC];
    __shared__ float qred[128];
    for (int k = threadIdx.x; k < n; k += 128) list[k] = cls_list[c * CAP_PC + k];
    __syncthreads();

    int col = g * 128 + threadIdx.x;
    float acc[8] = {0, 0, 0, 0, 0, 0, 0, 0};
    int k = 0;
    for (; k + 8 <= n; k += 8) {
#pragma unroll
        for (int u = 0; u < 8; u++)
            acc[u] += X[(size_t)list[k + u] * D + col];
    }
    for (; k < n; k++) acc[0] += X[(size_t)list[k] * D + col];
    float t = ((acc[0] + acc[1]) + (acc[2] + acc[3]))
            + ((acc[4] + acc[5]) + (acc[6] + acc[7]));
    S[(size_t)c * D + col] = t;

    if (g == 0) {  // colgroup 0 also writes Q_c
        float qs = 0.f;
        for (int k2 = threadIdx.x; k2 < n; k2 += 128) qs += sq[list[k2]];
        qred[threadIdx.x] = qs;
        __syncthreads();
        for (int s2 = 64; s2 > 0; s2 >>= 1) {
            if (threadIdx.x < s2) qred[threadIdx.x] += qred[threadIdx.x + s2];
            __syncthreads();
        }
        if (threadIdx.x == 0) Q[c] = qred[0];
    }
}

// ---------------- kernel 3: cross-class hinge term ----------------
// grid-stride over (i, chunk-of-8-j) work items; wave per item; 8 independent
// dot/reduce chains unrolled per wave for ILP. ~2048 chunks over 2048 waves.
__global__ __launch_bounds__(256) void k_cross(const float* __restrict__ X,
                                               const float* __restrict__ sq,
                                               const unsigned* __restrict__ cnt,
                                               const int* __restrict__ cls_list,
                                               float* __restrict__ cross_sum) {
    __shared__ int sm_m1, sm_m2, sm_na, sm_nb;
    __shared__ int A[CAP_PC], B[CAP_PC];
    if (threadIdx.x < 64) {  // wave 0: ballot-based m1/m2 (no serial scan)
        unsigned cn = cnt[threadIdx.x];
        unsigned long long mask = __ballot(cn != 0u);
        int m1 = 63 - __clzll(mask | 1ull);
        unsigned long long mask2 = mask & ~(1ull << m1);
        int m2 = mask2 ? (63 - __clzll(mask2)) : -1;
        if (threadIdx.x == 0) {
            sm_m1 = m1; sm_m2 = m2;
            sm_nb = (int)min(cnt[m1], (unsigned)CAP_PC);
            sm_na = (m2 >= 0) ? (int)min(cnt[m2], (unsigned)CAP_PC) : 0;
        }
    }
    __syncthreads();
    int na = sm_na, nb = sm_nb, m1 = sm_m1, m2 = sm_m2;
    if (na == 0 || nb == 0) return;
    for (int k = threadIdx.x; k < na; k += 256) A[k] = cls_list[m2 * CAP_PC + k];
    for (int k = threadIdx.x; k < nb; k += 256) B[k] = cls_list[m1 * CAP_PC + k];
    __syncthreads();

    int wv = threadIdx.x >> 6, lane = threadIdx.x & 63;
    int gw = blockIdx.x * 4 + wv, nw = gridDim.x * 4;
    int nbc = (nb + 7) >> 3;       // j-chunks of 8
    int nchunk = na * nbc;
    float hs = 0.f;
    for (int ch = gw; ch < nchunk; ch += nw) {
        int ai = ch / nbc;
        int bc = ch - ai * nbc;
        int i = A[ai];
        const float4* Xi = (const float4*)(X + (size_t)i * D);
        float4 ia = Xi[lane * 2], ib = Xi[lane * 2 + 1];
        float sqi = sq[i];
        int b0 = bc * 8;
#pragma unroll
        for (int u = 0; u < 8; u++) {
            int bi = b0 + u;
            int j = B[bi < nb ? bi : 0];
            const float4* Xj = (const float4*)(X + (size_t)j * D);
            float4 ja = Xj[lane * 2], jb = Xj[lane * 2 + 1];
            float d = ia.x * ja.x + ia.y * ja.y + ia.z * ja.z + ia.w * ja.w
                    + ib.x * jb.x + ib.y * jb.y + ib.z * jb.z + ib.w * jb.w;
#pragma unroll
            for (int off = 1; off < 64; off <<= 1) d += __shfl_xor(d, off);
            float d2 = fmaxf(sqi + sq[j] - 2.f * d, 0.f);
            float h = fmaxf(1.f - sqrtf(d2), 0.f);
            if (bi < nb) hs += h * h;
        }
    }
    if (lane == 0 && hs != 0.f) atomicAdd(cross_sum, hs);
}

// ---------------- kernel 4: final combine (double precision) ----------------
__global__ __launch_bounds__(256) void k_final(const float* __restrict__ S,
                                               const float* __restrict__ Q,
                                               const unsigned* __restrict__ cnt,
                                               const float* __restrict__ cross_sum,
                                               float* __restrict__ out) {
    __shared__ double r2[256], r1[256], rc[256];
    const float4* S4 = (const float4*)S;
    double t2 = 0.0;
    for (int i = threadIdx.x; i < C * D / 4; i += 256) {
        float4 s = S4[i];
        t2 += (double)s.x * s.x + (double)s.y * s.y
            + (double)s.z * s.z + (double)s.w * s.w;
    }
    double t1 = 0.0, pc = 0.0;
    if (threadIdx.x < C) {
        double nc = (double)cnt[threadIdx.x];
        t1 = nc * (double)Q[threadIdx.x];
        pc = nc * (nc - 1.0) * 0.5;
    }
    r2[threadIdx.x] = t2;
    r1[threadIdx.x] = t1;
    rc[threadIdx.x] = pc;
    __syncthreads();
    for (int s = 128; s > 0; s >>= 1) {
        if (threadIdx.x < s) {
            r2[threadIdx.x] += r2[threadIdx.x + s];
            r1[threadIdx.x] += r1[threadIdx.x + s];
            rc[threadIdx.x] += rc[threadIdx.x + s];
        }
        __syncthreads();
    }
    if (threadIdx.x == 0) {
        double same = (rc[0] > 0.0) ? (r1[0] - r2[0]) / rc[0] : 0.0;
        double diff = (double)cross_sum[0] / TOTAL_PAIRS;
        out[0] = (float)(same + diff);
    }
}

extern "C" void kernel_launch(void* const* d_in, const int* in_sizes, int n_in,
                              void* d_out, int out_size, void* d_ws, size_t ws_size,
                              hipStream_t stream) {
    const float* X = (const float*)d_in[0];   // outputs [N, D] fp32
    const float* L = (const float*)d_in[1];   // labels  [N, C] fp32
    float* ws = (float*)d_ws;

    float* S = ws;                               // 32768
    float* Q = ws + 32768;                       // 64
    unsigned* cnt = (unsigned*)(ws + 32832);     // 64
    float* cross = ws + 32896;                   // 1
    int* lbl = (int*)(ws + 32900);               // N
    float* sq = ws + 41092;                      // N
    int* cls_list = (int*)(ws + 49284);          // C * CAP_PC
    float* out = (float*)d_out;

    // zero cnt[64] + cross (contiguous): graph-capturable async memset
    hipMemsetAsync(cnt, 0, 65 * sizeof(unsigned), stream);

    hipLaunchKernelGGL(k_rows, dim3(N / 4), dim3(256), 0, stream,
                       X, L, lbl, sq, cnt, cls_list);
    hipLaunchKernelGGL(k_classsum, dim3(C * 4), dim3(128), 0, stream,
                       X, cls_list, cnt, sq, S, Q);
    hipLaunchKernelGGL(k_cross, dim3(512), dim3(256), 0, stream,
                       X, sq, cnt, cls_list, cross);
    hipLaunchKernelGGL(k_final, dim3(1), dim3(256), 0, stream,
                       S, Q, cnt, cross, out);
}

// Round 3
// 105.169 us; speedup vs baseline: 2.0155x; 1.2590x over previous
//
#include <hip/hip_runtime.h>
#include <math.h>

// Problem constants (fixed by setup_inputs)
constexpr int N = 8192;   // rows
constexpr int D = 512;    // feature dim
constexpr int C = 64;     // classes
constexpr int CAP_PC = 512;      // per-class list cap (counts ~128 +/- 11)
constexpr int CAP_W = CAP_PC / 2; // per-wave staging cap in k_lists
constexpr double TOTAL_PAIRS = 33550336.0;  // N*(N-1)/2

// ws layout (32-bit elements):
//   [0, 32768)        S[c][d]   per-class column sums (memset 0, fp32 atomics)
//   [32768]           cross_sum (memset 0)
//   [32772, 32836)    Q[c]      (written by k_lists)
//   [32836, 32900)    cnt[c]    (written by k_lists)
//   [32900, 41092)    lbl[N]
//   [41092, 49284)    sq[N]
//   [49284, 82052)    cls_list[C][CAP_PC]

// ------- kernel 1: per-row argmax + sum-of-squares (no atomics) -------
// one wave per row; grid = N/4 blocks of 256
__global__ __launch_bounds__(256) void k_rows(const float* __restrict__ X,
                                              const float* __restrict__ L,
                                              int* __restrict__ lbl,
                                              float* __restrict__ sq) {
    int wv = threadIdx.x >> 6, lane = threadIdx.x & 63;
    int row = blockIdx.x * 4 + wv;  // grid covers N exactly

    // argmax over 64 label logits: lane l holds class l (first-max tie rule)
    float v = L[(size_t)row * C + lane];
    int idx = lane;
#pragma unroll
    for (int off = 1; off < 64; off <<= 1) {
        float ov = __shfl_xor(v, off);
        int oi = __shfl_xor(idx, off);
        if (ov > v || (ov == v && oi < idx)) { v = ov; idx = oi; }
    }

    // sum of squares: lane reads 8 contiguous floats (2x float4)
    const float4* Xr = (const float4*)(X + (size_t)row * D);
    float4 a = Xr[lane * 2], b = Xr[lane * 2 + 1];
    float s = a.x * a.x + a.y * a.y + a.z * a.z + a.w * a.w
            + b.x * b.x + b.y * b.y + b.z * b.z + b.w * b.w;
#pragma unroll
    for (int off = 1; off < 64; off <<= 1) s += __shfl_xor(s, off);

    if (lane == 0) { lbl[row] = idx; sq[row] = s; }
}

// ------- kernel 2: class lists via ballot compaction (deterministic) -------
// 64 blocks (one per class) x 256; wave w scans rows [w*2048, (w+1)*2048).
// lbl/sq are L2-hot (32 KB each). Also computes Q_c and cnt_c.
__global__ __launch_bounds__(256) void k_lists(const int* __restrict__ lbl,
                                               const float* __restrict__ sq,
                                               unsigned* __restrict__ cnt,
                                               float* __restrict__ Q,
                                               int* __restrict__ cls_list) {
    int c = blockIdx.x;
    int wv = threadIdx.x >> 6, lane = threadIdx.x & 63;
    __shared__ int stage[4][CAP_W];
    __shared__ unsigned wcnt[4];
    __shared__ float wq[4];

    unsigned my = 0;
    float qs = 0.f;
    int base = wv * (N / 4);
    for (int it = 0; it < (N / 4) / 64; it++) {
        int r = base + it * 64 + lane;
        bool m = (lbl[r] == c);
        unsigned long long mask = __ballot(m);
        if (m) {
            unsigned pos = my + (unsigned)__popcll(mask & ((1ull << lane) - 1ull));
            if (pos < CAP_W) stage[wv][pos] = r;
            qs += sq[r];
        }
        my += (unsigned)__popcll(mask);
    }
#pragma unroll
    for (int off = 1; off < 64; off <<= 1) qs += __shfl_xor(qs, off);
    if (lane == 0) { wcnt[wv] = my; wq[wv] = qs; }
    __syncthreads();

    unsigned pre = 0, tot = 0;
    for (int w = 0; w < 4; w++) { if (w < wv) pre += wcnt[w]; tot += wcnt[w]; }
    unsigned n = min(my, (unsigned)CAP_W);
    for (unsigned k = lane; k < n; k += 64) {
        unsigned dst = pre + k;
        if (dst < (unsigned)CAP_PC) cls_list[c * CAP_PC + dst] = stage[wv][k];
    }
    if (threadIdx.x == 0) {
        cnt[c] = min(tot, (unsigned)CAP_PC);
        Q[c] = (wq[0] + wq[1]) + (wq[2] + wq[3]);
    }
}

// ------- kernel 3: per-class column sums, row-split for parallelism -------
// grid = C * 4 colgroups * 4 rowsplits = 1024 blocks x 128 threads.
// Partial sums accumulate into S via fp32 atomics (S pre-zeroed).
constexpr int RSPLIT = 4;
__global__ __launch_bounds__(128) void k_classsum(const float* __restrict__ X,
                                                  const int* __restrict__ cls_list,
                                                  const unsigned* __restrict__ cnt,
                                                  float* __restrict__ S) {
    int b = blockIdx.x;
    int r = b & (RSPLIT - 1);
    int g = (b >> 2) & 3;
    int c = b >> 4;
    int n = (int)cnt[c];
    int col = g * 128 + threadIdx.x;
    const int* lp = cls_list + c * CAP_PC;

    float acc[8] = {0, 0, 0, 0, 0, 0, 0, 0};
    int k = r;
    for (; k + 7 * RSPLIT < n; k += 8 * RSPLIT) {
#pragma unroll
        for (int u = 0; u < 8; u++)
            acc[u] += X[(size_t)lp[k + u * RSPLIT] * D + col];
    }
    for (; k < n; k += RSPLIT) acc[0] += X[(size_t)lp[k] * D + col];
    float t = ((acc[0] + acc[1]) + (acc[2] + acc[3]))
            + ((acc[4] + acc[5]) + (acc[6] + acc[7]));
    if (t != 0.f) atomicAdd(&S[(size_t)c * D + col], t);
}

// ---------------- kernel 4: cross-class hinge term ----------------
// grid-stride over (i, chunk-of-8-j); wave per chunk; 8 independent
// dot/reduce chains unrolled for ILP.
__global__ __launch_bounds__(256) void k_cross(const float* __restrict__ X,
                                               const float* __restrict__ sq,
                                               const unsigned* __restrict__ cnt,
                                               const int* __restrict__ cls_list,
                                               float* __restrict__ cross_sum) {
    __shared__ int sm_m1, sm_m2, sm_na, sm_nb;
    __shared__ int A[CAP_PC], B[CAP_PC];
    if (threadIdx.x < 64) {  // wave 0: ballot-based m1/m2
        unsigned cn = cnt[threadIdx.x];
        unsigned long long mask = __ballot(cn != 0u);
        int m1 = 63 - __clzll(mask | 1ull);
        unsigned long long mask2 = mask & ~(1ull << m1);
        int m2 = mask2 ? (63 - __clzll(mask2)) : -1;
        if (threadIdx.x == 0) {
            sm_m1 = m1; sm_m2 = m2;
            sm_nb = (int)min(cnt[m1], (unsigned)CAP_PC);
            sm_na = (m2 >= 0) ? (int)min(cnt[m2], (unsigned)CAP_PC) : 0;
        }
    }
    __syncthreads();
    int na = sm_na, nb = sm_nb, m1 = sm_m1, m2 = sm_m2;
    if (na == 0 || nb == 0) return;
    for (int k = threadIdx.x; k < na; k += 256) A[k] = cls_list[m2 * CAP_PC + k];
    for (int k = threadIdx.x; k < nb; k += 256) B[k] = cls_list[m1 * CAP_PC + k];
    __syncthreads();

    int wv = threadIdx.x >> 6, lane = threadIdx.x & 63;
    int gw = blockIdx.x * 4 + wv, nw = gridDim.x * 4;
    int nbc = (nb + 7) >> 3;
    int nchunk = na * nbc;
    float hs = 0.f;
    for (int ch = gw; ch < nchunk; ch += nw) {
        int ai = ch / nbc;
        int bc = ch - ai * nbc;
        int i = A[ai];
        const float4* Xi = (const float4*)(X + (size_t)i * D);
        float4 ia = Xi[lane * 2], ib = Xi[lane * 2 + 1];
        float sqi = sq[i];
        int b0 = bc * 8;
#pragma unroll
        for (int u = 0; u < 8; u++) {
            int bi = b0 + u;
            int j = B[bi < nb ? bi : 0];
            const float4* Xj = (const float4*)(X + (size_t)j * D);
            float4 ja = Xj[lane * 2], jb = Xj[lane * 2 + 1];
            float d = ia.x * ja.x + ia.y * ja.y + ia.z * ja.z + ia.w * ja.w
                    + ib.x * jb.x + ib.y * jb.y + ib.z * jb.z + ib.w * jb.w;
#pragma unroll
            for (int off = 1; off < 64; off <<= 1) d += __shfl_xor(d, off);
            float d2 = fmaxf(sqi + sq[j] - 2.f * d, 0.f);
            float h = fmaxf(1.f - sqrtf(d2), 0.f);
            if (bi < nb) hs += h * h;
        }
    }
    if (lane == 0 && hs != 0.f) atomicAdd(cross_sum, hs);
}

// ---------------- kernel 5: final combine (double precision) ----------------
__global__ __launch_bounds__(256) void k_final(const float* __restrict__ S,
                                               const float* __restrict__ Q,
                                               const unsigned* __restrict__ cnt,
                                               const float* __restrict__ cross_sum,
                                               float* __restrict__ out) {
    __shared__ double r2[256], r1[256], rc[256];
    const float4* S4 = (const float4*)S;
    double t2 = 0.0;
    for (int i = threadIdx.x; i < C * D / 4; i += 256) {
        float4 s = S4[i];
        t2 += (double)s.x * s.x + (double)s.y * s.y
            + (double)s.z * s.z + (double)s.w * s.w;
    }
    double t1 = 0.0, pc = 0.0;
    if (threadIdx.x < C) {
        double nc = (double)cnt[threadIdx.x];
        t1 = nc * (double)Q[threadIdx.x];
        pc = nc * (nc - 1.0) * 0.5;
    }
    r2[threadIdx.x] = t2;
    r1[threadIdx.x] = t1;
    rc[threadIdx.x] = pc;
    __syncthreads();
    for (int s = 128; s > 0; s >>= 1) {
        if (threadIdx.x < s) {
            r2[threadIdx.x] += r2[threadIdx.x + s];
            r1[threadIdx.x] += r1[threadIdx.x + s];
            rc[threadIdx.x] += rc[threadIdx.x + s];
        }
        __syncthreads();
    }
    if (threadIdx.x == 0) {
        double same = (rc[0] > 0.0) ? (r1[0] - r2[0]) / rc[0] : 0.0;
        double diff = (double)cross_sum[0] / TOTAL_PAIRS;
        out[0] = (float)(same + diff);
    }
}

extern "C" void kernel_launch(void* const* d_in, const int* in_sizes, int n_in,
                              void* d_out, int out_size, void* d_ws, size_t ws_size,
                              hipStream_t stream) {
    const float* X = (const float*)d_in[0];   // outputs [N, D] fp32
    const float* L = (const float*)d_in[1];   // labels  [N, C] fp32
    float* ws = (float*)d_ws;

    float* S = ws;                               // [0, 32768)
    float* cross = ws + 32768;                   // [32768]
    float* Q = ws + 32772;                       // 64
    unsigned* cnt = (unsigned*)(ws + 32836);     // 64
    int* lbl = (int*)(ws + 32900);               // N
    float* sq = ws + 41092;                      // N
    int* cls_list = (int*)(ws + 49284);          // C * CAP_PC
    float* out = (float*)d_out;

    // zero S + cross_sum (contiguous 32769 floats)
    hipMemsetAsync(S, 0, 32769 * sizeof(float), stream);

    hipLaunchKernelGGL(k_rows, dim3(N / 4), dim3(256), 0, stream, X, L, lbl, sq);
    hipLaunchKernelGGL(k_lists, dim3(C), dim3(256), 0, stream,
                       lbl, sq, cnt, Q, cls_list);
    hipLaunchKernelGGL(k_classsum, dim3(C * 4 * RSPLIT), dim3(128), 0, stream,
                       X, cls_list, cnt, S);
    hipLaunchKernelGGL(k_cross, dim3(512), dim3(256), 0, stream,
                       X, sq, cnt, cls_list, cross);
    hipLaunchKernelGGL(k_final, dim3(1), dim3(256), 0, stream,
                       S, Q, cnt, cross, out);
}